// Round 21
// baseline (35.409 us; speedup 1.0000x reference)
//
#include <hip/hip_runtime.h>
#include <hip/hip_bf16.h>
#include <math.h>

// Problem constants
#define Bn 8
#define Cn 64
#define Hn 128
#define Wn 128
#define Rn 4

typedef __bf16 v8bf __attribute__((ext_vector_type(8)));
typedef float  v16f __attribute__((ext_vector_type(16)));

__device__ __forceinline__ float leaky(float x) { return x >= 0.f ? x : 0.1f * x; }

__device__ __forceinline__ unsigned bf16pair(float a, float b) {
    __hip_bfloat16 ha = __float2bfloat16(a);
    __hip_bfloat16 hb = __float2bfloat16(b);
    return (unsigned)*reinterpret_cast<unsigned short*>(&ha) |
           ((unsigned)*reinterpret_cast<unsigned short*>(&hb) << 16);
}

// VALU wave-wide shifts via DPP (no DS pipe). bound_ctrl -> out-of-range = 0,
// which matches the image border semantics at lanes 0 / 63 exactly.
__device__ __forceinline__ float dpp_up1(float x) {    // lane n <- lane n-1; lane0 = 0
    int r = __builtin_amdgcn_update_dpp(0, __builtin_bit_cast(int, x),
                                        0x138 /*wave_shr:1*/, 0xf, 0xf, true);
    return __builtin_bit_cast(float, r);
}
__device__ __forceinline__ float dpp_down1(float x) {  // lane n <- lane n+1; lane63 = 0
    int r = __builtin_amdgcn_update_dpp(0, __builtin_bit_cast(int, x),
                                        0x130 /*wave_shl:1*/, 0xf, 0xf, true);
    return __builtin_bit_cast(float, r);
}

// ---------------------------------------------------------------------------
// Kernel A: per-batch dynamic depthwise kernels + channel attn; block Bn
// converts w_conv -> bf16 [o][c].
//   kern_g[b][c][r][12]  (b*3072 + c*48 + r*12 + kk; slots 9..11 pad)
//   att_g [b][r][c]
// ---------------------------------------------------------------------------
__global__ __launch_bounds__(256) void precomp_kernel(
    const float* __restrict__ deg, const float* __restrict__ w_k1,
    const float* __restrict__ w_k2, const float* __restrict__ w_ca1,
    const float* __restrict__ w_ca2, const float* __restrict__ w_conv,
    float* __restrict__ kern_g, float* __restrict__ att_g,
    unsigned short* __restrict__ wbf)
{
    const int tid = threadIdx.x;
    if (blockIdx.x == Bn) {                       // w_conv -> bf16
        for (int f = tid; f < Cn * Cn; f += 256) {
            __hip_bfloat16 hx = __float2bfloat16(w_conv[f]);
            wbf[f] = *reinterpret_cast<unsigned short*>(&hx);
        }
        return;
    }
    const int b = blockIdx.x;
    __shared__ float y_s[64], a_s[64];
    if (tid < 64) {
        float sy = 0.f, sa = 0.f;
#pragma unroll 8
        for (int j = 0; j < 64; ++j) {
            float d = deg[b * 64 + j];
            sy += d * w_k1[tid * 64 + j];
            sa += d * w_ca1[tid * 64 + j];
        }
        y_s[tid] = leaky(sy);
        a_s[tid] = leaky(sa);
    }
    __syncthreads();
    for (int f = tid; f < Cn * Rn * 9; f += 256) {
        int c = f / 36;
        int j = f - c * 36;
        int r = j / 9;
        int kk = j - r * 9;
        int o = c * 9 + kk;
        const float* wp = &w_k2[(r * 576 + o) * 16];
        const float* yp = &y_s[r * 16];
        float s = 0.f;
#pragma unroll
        for (int i = 0; i < 16; ++i) s += yp[i] * wp[i];
        kern_g[b * 3072 + c * 48 + r * 12 + kk] = s;
    }
    {
        int r = tid >> 6, o = tid & 63;
        const float* wp = &w_ca2[(r * 64 + o) * 16];
        const float* ap = &a_s[r * 16];
        float s = 0.f;
#pragma unroll
        for (int i = 0; i < 16; ++i) s += ap[i] * wp[i];
        att_g[b * 256 + tid] = 1.f / (1.f + expf(-s));
    }
}

// ---------------------------------------------------------------------------
// Main kernel: one block per (b, row-pair), 1024 threads = 16 waves.
// h0 = 2*hp, rows {h0, h0+1}. 2 blocks/CU (54 KB LDS) = 32 waves/CU.
// Phase 1: wave g in [0,16) computes channels [4g,4g+4) for BOTH rows;
//   lane owns cols (2*lane, 2*lane+1). Per channel: 4 float2 row loads
//   (rows h0-1..h0+2, shared between the two outputs), 8 DPP shifts,
//   4 kern b128-pair reads (r1 per row+col), 4 b32 pair-writes per 2 ch.
// Phase 2: wave v -> (rr = v>>3, oh, wt): 32x32 MFMA tile of row rr.
// ---------------------------------------------------------------------------
__global__ __launch_bounds__(1024) void da_main(
    const float* __restrict__ x0, const float* __restrict__ q_map,
    const unsigned short* __restrict__ wbf, const float* __restrict__ b_conv,
    const float* __restrict__ w_g1, const float* __restrict__ b_g1,
    const float* __restrict__ w_g2, const float* __restrict__ b_g2,
    const float* __restrict__ kern_g, const float* __restrict__ att_g,
    float* __restrict__ out)
{
    __shared__ __align__(16) float kern_lds[Cn * 48];           // 12 KB
    __shared__ __align__(16) unsigned short wc_lds[8][Cn][8];   // 8 KB
    __shared__ __align__(16) unsigned short t_lds[2][Wn * Cn];  // 32 KB ([rr][w][c], swz)
    __shared__ float att_lds[Rn * 68];                          // 1.1 KB
    __shared__ float bias_lds[Cn];                              // 0.25 KB
    __shared__ unsigned ridx[2][Wn];                            // 1 KB  r1 | r2<<16

    const int tid = threadIdx.x;
    const int ob = blockIdx.x;
    // XCD-aware swizzle: XCD i gets batch i (4 MB image == one L2).
    const int sb = ((ob & 7) << 6) | (ob >> 3);
    const int b = sb >> 6;
    const int hp = sb & 63;
    const int h0 = 2 * hp;

    const int lane = tid & 63;
    const int g = tid >> 6;               // wave id: channels [4g, 4g+4)
    const int w0 = 2 * lane;              // this lane's column pair
    const int w1 = w0 + 1;

    // ---- phase 0: staging ----
    for (int f = tid; f < Cn * 48; f += 1024)
        kern_lds[f] = kern_g[b * 3072 + f];
    if (tid < 512) {                      // wc subtiles: conflict-free b128
        int cq = tid & 7, o = tid >> 3;
        *(v8bf*)&wc_lds[cq][o][0] = *(const v8bf*)&wbf[o * 64 + cq * 8];
    }
    if (tid < 256) att_lds[(tid >> 6) * 68 + (tid & 63)] = att_g[b * 256 + tid];
    if (tid < 64) bias_lds[tid] = b_conv[tid];

    // routing: one (row, col) pair per thread (tid < 256)
    if (tid < 256) {
        const int rr = tid >> 7;
        const int wc = tid & 127;
        const int row0 = h0 + rr;
        float qv[9];
#pragma unroll
        for (int dh = 0; dh < 3; ++dh) {
            int row = row0 - 1 + dh;
#pragma unroll
            for (int dw = 0; dw < 3; ++dw) {
                int col = wc - 1 + dw;
                qv[dh * 3 + dw] = (row >= 0 && row < Hn && col >= 0 && col < Wn)
                                      ? q_map[(b * Hn + row) * Wn + col] : 0.f;
            }
        }
        float best1 = -1e30f, best2 = -1e30f;
        int r1 = 0, r2 = 0;
#pragma unroll
        for (int r = 0; r < Rn; ++r) {
            float s1 = b_g1[r], s2 = b_g2[r];
#pragma unroll
            for (int k = 0; k < 9; ++k) {
                s1 += qv[k] * w_g1[r * 9 + k];
                s2 += qv[k] * w_g2[r * 9 + k];
            }
            if (s1 > best1) { best1 = s1; r1 = r; }   // strict > == first argmax
            if (s2 > best2) { best2 = s2; r2 = r; }
        }
        ridx[rr][wc] = (unsigned)r1 | ((unsigned)r2 << 16);
    }
    __syncthreads();

    // ---- phase 1: 2-row column-pair depthwise, 1-deep pipelined, DPP ----
    const bool okm = (h0 > 0);            // row h0-1 exists
    const bool okp = (hp < 63);           // row h0+2 exists
    const float* xbase = x0 + ((size_t)(b * Cn) * Hn + h0) * Wn + w0;
    const int r1a0 = (int)(ridx[0][w0] & 0xffffu);
    const int r1b0 = (int)(ridx[0][w1] & 0xffffu);
    const int r1a1 = (int)(ridx[1][w0] & 0xffffu);
    const int r1b1 = (int)(ridx[1][w1] & 0xffffu);
    const int swz = (lane & 7) << 4;      // write == read swizzle ((w>>1)&7)<<4

    // prefetch buffer: 4 row-taps (h0-1, h0, h0+1, h0+2), 1 channel ahead
    float2 nA, nB, nC, nD;

#define LOADC(CI)                                                         \
    do {                                                                  \
        const float* xc = xbase + (4 * g + (CI)) * (Hn * Wn);             \
        nA = okm ? *(const float2*)(xc - Wn) : make_float2(0.f, 0.f);     \
        nB = *(const float2*)xc;                                          \
        nC = *(const float2*)(xc + Wn);                                   \
        nD = okp ? *(const float2*)(xc + 2 * Wn) : make_float2(0.f, 0.f); \
    } while (0)

    float tp00 = 0.f, tp01 = 0.f, tp10 = 0.f, tp11 = 0.f;  // prev channel
    LOADC(0);
#pragma unroll
    for (int ci = 0; ci < 4; ++ci) {
        float2 A = nA, B = nB, C = nC, D = nD;
        if (ci < 3) LOADC(ci + 1);                 // issue next channel's loads

        // neighbor taps via DPP (lane0/63 auto-zero = image borders)
        float lA = dpp_up1(A.y), lB = dpp_up1(B.y), lC = dpp_up1(C.y), lD = dpp_up1(D.y);
        float rA = dpp_down1(A.x), rB = dpp_down1(B.x), rC = dpp_down1(C.x), rD = dpp_down1(D.x);

        const int c = 4 * g + ci;
        const float* kc = &kern_lds[c * 48];
        // row 0 (taps A,B,C)
        const float* kpa = kc + r1a0 * 12;
        float4 a03 = *(const float4*)kpa;
        float4 a47 = *(const float4*)(kpa + 4);
        float a8 = kpa[8];
        float t00 = lA  * a03.x + A.x * a03.y + A.y * a03.z
                  + lB  * a03.w + B.x * a47.x + B.y * a47.y
                  + lC  * a47.z + C.x * a47.w + C.y * a8;
        const float* kpb = kc + r1b0 * 12;
        float4 b03 = *(const float4*)kpb;
        float4 b47 = *(const float4*)(kpb + 4);
        float b8 = kpb[8];
        float t01 = A.x * b03.x + A.y * b03.y + rA  * b03.z
                  + B.x * b03.w + B.y * b47.x + rB  * b47.y
                  + C.x * b47.z + C.y * b47.w + rC  * b8;
        // row 1 (taps B,C,D)
        const float* kpc = kc + r1a1 * 12;
        float4 c03 = *(const float4*)kpc;
        float4 c47 = *(const float4*)(kpc + 4);
        float c8 = kpc[8];
        float t10 = lB  * c03.x + B.x * c03.y + B.y * c03.z
                  + lC  * c03.w + C.x * c47.x + C.y * c47.y
                  + lD  * c47.z + D.x * c47.w + D.y * c8;
        const float* kpd = kc + r1b1 * 12;
        float4 d03 = *(const float4*)kpd;
        float4 d47 = *(const float4*)(kpd + 4);
        float d8 = kpd[8];
        float t11 = B.x * d03.x + B.y * d03.y + rB  * d03.z
                  + C.x * d03.w + C.y * d47.x + rC  * d47.y
                  + D.x * d47.z + D.y * d47.w + rD  * d8;

        t00 = leaky(t00); t01 = leaky(t01);
        t10 = leaky(t10); t11 = leaky(t11);

        if (ci & 1) {                     // write completed channel pairs
            const int cbyte = (4 * g + ci - 1) * 2;
            *(unsigned*)((char*)&t_lds[0][0] + w0 * 128 + (cbyte ^ swz)) = bf16pair(tp00, t00);
            *(unsigned*)((char*)&t_lds[0][0] + w1 * 128 + (cbyte ^ swz)) = bf16pair(tp01, t01);
            *(unsigned*)((char*)&t_lds[1][0] + w0 * 128 + (cbyte ^ swz)) = bf16pair(tp10, t10);
            *(unsigned*)((char*)&t_lds[1][0] + w1 * 128 + (cbyte ^ swz)) = bf16pair(tp11, t11);
        } else {
            tp00 = t00; tp01 = t01; tp10 = t10; tp11 = t11;
        }
    }
#undef LOADC
    __syncthreads();

    // ---- phase 2: MFMA channel mix + fused epilogue (per row) ----
    const int v = tid >> 6;               // wave 0..15
    const int rr = v >> 3;                // row within pair
    const int u = v & 7;
    const int wt = u & 3;                 // w-tile (32 cols)
    const int oh = u >> 2;                // o-half (32 rows)
    const int col = lane & 31;
    const int kh = lane >> 5;
    const int wn = wt * 32 + col;         // this lane's output column
    const int h = h0 + rr;

    v8bf Bf[4];
#pragma unroll
    for (int ks = 0; ks < 4; ++ks) {
        int cbyte = (16 * ks + 8 * kh) * 2;
        Bf[ks] = *(const v8bf*)((const char*)&t_lds[rr][0] + wn * 128 +
                                (cbyte ^ (((wn >> 1) & 7) << 4)));
    }

    v16f acc;
#pragma unroll
    for (int i = 0; i < 16; ++i) acc[i] = 0.f;

#pragma unroll
    for (int ks = 0; ks < 4; ++ks) {
        const int cq = 2 * ks + kh;
        v8bf Af = *(const v8bf*)&wc_lds[cq][oh * 32 + col][0];
        acc = __builtin_amdgcn_mfma_f32_32x32x16_bf16(Af, Bf[ks], acc, 0, 0, 0);
    }

    const int r2e = (int)(ridx[rr][wn] >> 16);
    const float* xcol = x0 + ((size_t)(b * Cn + oh * 32) * Hn + h) * Wn + wn;
    float* ocol = out + ((size_t)(b * Cn + oh * 32) * Hn + h) * Wn + wn;

#pragma unroll
    for (int r = 0; r < 16; ++r) {
        int row = (r & 3) + 8 * (r >> 2) + 4 * kh;     // 0..31 within tile
        int o = oh * 32 + row;
        float xv = xcol[(size_t)row * (Hn * Wn)];      // L2 hit
        float res = acc[r] + bias_lds[o] + xv * att_lds[r2e * 68 + o];
        ocol[(size_t)row * (Hn * Wn)] = res;           // 128B coalesced
    }
}

// ---------------------------------------------------------------------------
extern "C" void kernel_launch(void* const* d_in, const int* in_sizes, int n_in,
                              void* d_out, int out_size, void* d_ws, size_t ws_size,
                              hipStream_t stream)
{
    const float* x0     = (const float*)d_in[0];
    const float* deg    = (const float*)d_in[1];
    const float* q_map  = (const float*)d_in[2];
    const float* w_k1   = (const float*)d_in[3];
    const float* w_k2   = (const float*)d_in[4];
    const float* w_conv = (const float*)d_in[5];
    const float* b_conv = (const float*)d_in[6];
    const float* w_ca1  = (const float*)d_in[7];
    const float* w_ca2  = (const float*)d_in[8];
    const float* w_g1   = (const float*)d_in[9];
    const float* b_g1   = (const float*)d_in[10];
    const float* w_g2   = (const float*)d_in[11];
    const float* b_g2   = (const float*)d_in[12];
    float* outp   = (float*)d_out;
    float* kern_g = (float*)d_ws;                           // 8*3072 floats
    float* att_g  = kern_g + Bn * 3072;                     // 8*256 floats
    unsigned short* wbf = (unsigned short*)(att_g + Bn * 256);  // 4096 bf16

    precomp_kernel<<<Bn + 1, 256, 0, stream>>>(deg, w_k1, w_k2, w_ca1, w_ca2,
                                               w_conv, kern_g, att_g, wbf);
    da_main<<<Bn * (Hn / 2), 1024, 0, stream>>>(x0, q_map, wbf, b_conv,
                                                w_g1, b_g1, w_g2, b_g2,
                                                kern_g, att_g, outp);
}